// Round 1
// baseline (443.786 us; speedup 1.0000x reference)
//
#include <hip/hip_runtime.h>
#include <hip/hip_bf16.h>

// ---------------- ArcFace constants ----------------
#define ARC_S    30.0f
#define ARC_COSM 0.8775825618903728f   // cos(0.5)
#define ARC_SINM 0.4794255386042030f   // sin(0.5)
#define ARC_TH  -0.8775825618903728f   // cos(pi-0.5)
#define ARC_MM   0.2397127693021015f   // sin(pi-0.5)*0.5

#define B_ROWS 512
#define D_DIM  512
#define C_CLS  100000
#define C_PAD  100096                  // 782 * 128

typedef float  floatx4 __attribute__((ext_vector_type(4)));
typedef __bf16 bf16x8  __attribute__((ext_vector_type(8)));

// ---------------------------------------------------------------------------
// Row L2-normalize (row length fixed = 512 floats) -> bf16.
// One wave per row; 4 rows per 256-thread block. Rows >= valid_rows get zeros.
// ---------------------------------------------------------------------------
__global__ __launch_bounds__(256) void normalize_rows_512(
    const float* __restrict__ src, __bf16* __restrict__ dst, int valid_rows)
{
    const int lane = threadIdx.x & 63;
    const int wave = threadIdx.x >> 6;
    const long long row = (long long)blockIdx.x * 4 + wave;

    __bf16* drow = dst + row * D_DIM;

    if (row >= valid_rows) {
        bf16x8 z;
        #pragma unroll
        for (int i = 0; i < 8; i++) z[i] = (__bf16)0.0f;
        *(bf16x8*)(drow + lane * 8) = z;
        return;
    }

    const float4* rp = (const float4*)(src + row * D_DIM);
    float4 p0 = rp[lane * 2];
    float4 p1 = rp[lane * 2 + 1];

    float ss = p0.x*p0.x + p0.y*p0.y + p0.z*p0.z + p0.w*p0.w
             + p1.x*p1.x + p1.y*p1.y + p1.z*p1.z + p1.w*p1.w;
    #pragma unroll
    for (int m = 32; m >= 1; m >>= 1) ss += __shfl_xor(ss, m, 64);

    const float scale = 1.0f / fmaxf(sqrtf(ss), 1e-12f);

    bf16x8 v;
    v[0] = (__bf16)(p0.x * scale);
    v[1] = (__bf16)(p0.y * scale);
    v[2] = (__bf16)(p0.z * scale);
    v[3] = (__bf16)(p0.w * scale);
    v[4] = (__bf16)(p1.x * scale);
    v[5] = (__bf16)(p1.y * scale);
    v[6] = (__bf16)(p1.z * scale);
    v[7] = (__bf16)(p1.w * scale);
    *(bf16x8*)(drow + lane * 8) = v;
}

// ---------------------------------------------------------------------------
// bf16 MFMA GEMM (M=512, N=100096 padded, K=512) + fused ArcFace epilogue.
// 256x128 tile per block, 512 threads = 8 waves (4M x 2N), wave = 64x64 out.
//
// v2: pipelined K-loop (T3 minimum-2-phase). BK 64->32 so DOUBLE-BUFFERED
// LDS stays at 49KB (As 2x16K + Bs 2x8K + labels) -> 3 blocks/CU retained.
// Per K-step: issue 3 global_load_lds for tile t+1 into buf^1, ds_read+MFMA
// tile t from buf, then ONE __syncthreads() whose vmcnt(0) drain lands after
// ~16 MFMA + 8 ds_read of compute (loads already complete) instead of the
// old cold stage->drain->compute (0-phase) that exposed full load latency
// to all 8 waves every K-step.  s_setprio(1) wraps the MFMA cluster (T5).
//
// LDS swizzle re-derived for 4-chunk rows: slot kc holds gmem chunk
// kc ^ ((row>>1)&3).  Wave read = 16 rows x 4 fch-chunks = all 64 slots of
// 16 rows exactly once -> 8 dwords/bank uniform = conflict-free minimum.
// Grid swizzle unchanged: paired m-tiles (ids b, b+8) share the n-tile's W
// data through the same XCD's L2.
// ---------------------------------------------------------------------------
#define BM 256
#define BN 128
#define BK 32
#define KSTEPS  (D_DIM / BK)   // 16
#define N_TILES 782            // C_PAD / BN
#define GRID_B  1568           // 16 * ceil(N_TILES*2 / 16)

__device__ inline void async_load_16B(__bf16* lds, const __bf16* gmem)
{
    __builtin_amdgcn_global_load_lds(
        (const __attribute__((address_space(1))) void*)gmem,
        (__attribute__((address_space(3))) void*)lds,
        16, 0, 0);
}

__global__ __launch_bounds__(512, 4) void gemm_arcface(
    const __bf16* __restrict__ A,
    const __bf16* __restrict__ W,
    const int*    __restrict__ label,
    float*        __restrict__ out)
{
    // XCD-aware swizzle: groups of 16 consecutive ids cover 8 n-tiles x 2
    // m-tiles such that the m-pair ids differ by exactly 8 (same XCD).
    const int b  = blockIdx.x;
    const int nt = (b & 7) + 8 * (b >> 4);
    const int mt = (b >> 3) & 1;
    if (nt >= N_TILES) return;   // uniform tail guard (8 idle blocks)

    __shared__ __bf16 As[2][BM * BK];   // 2 x 16 KB
    __shared__ __bf16 Bs[2][BN * BK];   // 2 x  8 KB
    __shared__ int    sLab[BM];

    const int tid = threadIdx.x;
    const int m0  = mt * BM;
    const int n0  = nt * BN;

    if (tid < BM) sLab[tid] = label[m0 + tid];

    const int lane = tid & 63;
    const int wave = tid >> 6;
    const int wr   = wave >> 1;        // 0..3 (M direction, 64 rows each)
    const int wc   = wave & 1;         // 0..1 (N direction, 64 cols each)
    const int frow = lane & 15;        // row within 16x16 frag
    const int fch  = lane >> 4;        // k-chunk sub-index 0..3

    // ---- staging descriptors (computed once; pointers advance by +BK) ----
    // Per k-step chunks of 16B: A has 1024 (2/thread: i=tid, tid+512),
    // B has 512 (1/thread: i=tid).  row = i>>2, kc = i&3.
    // Note (tid+512) has same kc and (row>>1)&3 pattern: a1 = a0 + 128 rows.
    const int srow = tid >> 2;
    const int skc  = (tid & 3) ^ ((tid >> 3) & 3);   // swizzled gmem chunk

    const __bf16* gA0 = A + (long long)(m0 + srow) * D_DIM + skc * 8;
    const __bf16* gA1 = gA0 + (long long)128 * D_DIM;
    const __bf16* gB0 = W + (long long)(n0 + srow) * D_DIM + skc * 8;

    // ---- ds_read offsets (element units; fixed across K-loop) ----
    int aoff[4], boff[4];
    #pragma unroll
    for (int i = 0; i < 4; i++) {
        const int ar = wr * 64 + i * 16 + frow;
        aoff[i] = ar * BK + ((fch ^ ((ar >> 1) & 3)) << 3);
        const int br = wc * 64 + i * 16 + frow;
        boff[i] = br * BK + ((fch ^ ((br >> 1) & 3)) << 3);
    }

    floatx4 acc[4][4];
    #pragma unroll
    for (int i = 0; i < 4; i++)
        #pragma unroll
        for (int j = 0; j < 4; j++)
            acc[i][j] = (floatx4)(0.0f);

    // ---- prologue: stage tile 0 into buffer 0 ----
    async_load_16B(&As[0][tid * 8],         gA0);
    async_load_16B(&As[0][(tid + 512) * 8], gA1);
    async_load_16B(&Bs[0][tid * 8],         gB0);
    __syncthreads();

    // ---- pipelined K-loop: prefetch t+1 while computing t ----
    #pragma unroll 2
    for (int t = 0; t < KSTEPS; ++t) {
        const int cur = t & 1;
        if (t + 1 < KSTEPS) {
            const int ko = (t + 1) * BK;
            async_load_16B(&As[cur ^ 1][tid * 8],         gA0 + ko);
            async_load_16B(&As[cur ^ 1][(tid + 512) * 8], gA1 + ko);
            async_load_16B(&Bs[cur ^ 1][tid * 8],         gB0 + ko);
        }

        bf16x8 a[4], bb[4];
        #pragma unroll
        for (int i = 0; i < 4; i++) a[i]  = *(const bf16x8*)(&As[cur][aoff[i]]);
        #pragma unroll
        for (int j = 0; j < 4; j++) bb[j] = *(const bf16x8*)(&Bs[cur][boff[j]]);

        __builtin_amdgcn_s_setprio(1);
        #pragma unroll
        for (int i = 0; i < 4; i++)
            #pragma unroll
            for (int j = 0; j < 4; j++)
                acc[i][j] = __builtin_amdgcn_mfma_f32_16x16x32_bf16(
                    a[i], bb[j], acc[i][j], 0, 0, 0);
        __builtin_amdgcn_s_setprio(0);

        if (t + 1 < KSTEPS) __syncthreads();   // prefetched tile now ready
    }

    // ---- fused ArcFace epilogue ----
    // D layout: row (M) = (lane>>4)*4 + reg, col (N) = lane&15
    const int mrow = (lane >> 4) * 4;
    const int ncol = lane & 15;

    #pragma unroll
    for (int i = 0; i < 4; i++) {
        #pragma unroll
        for (int r = 0; r < 4; r++) {
            const int ml  = wr * 64 + i * 16 + mrow + r;
            const int m   = m0 + ml;
            const int lab = sLab[ml];
            float* orow = out + (long long)m * C_CLS;
            #pragma unroll
            for (int j = 0; j < 4; j++) {
                const int cls = n0 + wc * 64 + j * 16 + ncol;
                if (cls < C_CLS) {
                    float c = fminf(fmaxf(acc[i][j][r], -1.0f), 1.0f);
                    float t = fminf(fmaxf(1.0f - c * c, 1e-9f), 1.0f);
                    float s = sqrtf(t);
                    float phi = c * ARC_COSM - s * ARC_SINM;
                    phi = (c > ARC_TH) ? phi : (c - ARC_MM);
                    float o = ((lab == cls) ? phi : c) * ARC_S;
                    orow[cls] = o;
                }
            }
        }
    }
}

// ---------------------------------------------------------------------------
extern "C" void kernel_launch(void* const* d_in, const int* in_sizes, int n_in,
                              void* d_out, int out_size, void* d_ws, size_t ws_size,
                              hipStream_t stream)
{
    const float* inp    = (const float*)d_in[0];
    const int*   label  = (const int*)d_in[1];
    const float* weight = (const float*)d_in[2];
    float*       out    = (float*)d_out;

    // workspace layout: A_bf16 [512*512], W_bf16 [C_PAD*512]
    __bf16* A = (__bf16*)d_ws;
    __bf16* W = A + (size_t)B_ROWS * D_DIM;

    // K1: normalize input rows (512 rows, 4 rows/block)
    normalize_rows_512<<<B_ROWS / 4, 256, 0, stream>>>(inp, A, B_ROWS);
    // K2: normalize weight rows (+ zero-fill padding to C_PAD)
    normalize_rows_512<<<C_PAD / 4, 256, 0, stream>>>(weight, W, C_CLS);
    // K3: GEMM + ArcFace epilogue (pipelined, XCD-paired grid, 256x128 tiles)
    gemm_arcface<<<GRID_B, 512, 0, stream>>>(A, W, label, out);
}

// Round 2
// 430.375 us; speedup vs baseline: 1.0312x; 1.0312x over previous
//
#include <hip/hip_runtime.h>
#include <hip/hip_bf16.h>

// ---------------- ArcFace constants ----------------
#define ARC_S    30.0f
#define ARC_COSM 0.8775825618903728f   // cos(0.5)
#define ARC_SINM 0.4794255386042030f   // sin(0.5)
#define ARC_TH  -0.8775825618903728f   // cos(pi-0.5)
#define ARC_MM   0.2397127693021015f   // sin(pi-0.5)*0.5

#define B_ROWS 512
#define D_DIM  512
#define C_CLS  100000
#define C_PAD  100096                  // 782 * 128

typedef float  floatx4 __attribute__((ext_vector_type(4)));
typedef __bf16 bf16x8  __attribute__((ext_vector_type(8)));

// ---------------------------------------------------------------------------
// Row L2-normalize (row length fixed = 512 floats) -> bf16.
// One wave per row; 4 rows per 256-thread block. Rows >= valid_rows get zeros.
// ---------------------------------------------------------------------------
__global__ __launch_bounds__(256) void normalize_rows_512(
    const float* __restrict__ src, __bf16* __restrict__ dst, int valid_rows)
{
    const int lane = threadIdx.x & 63;
    const int wave = threadIdx.x >> 6;
    const long long row = (long long)blockIdx.x * 4 + wave;

    __bf16* drow = dst + row * D_DIM;

    if (row >= valid_rows) {
        bf16x8 z;
        #pragma unroll
        for (int i = 0; i < 8; i++) z[i] = (__bf16)0.0f;
        *(bf16x8*)(drow + lane * 8) = z;
        return;
    }

    const float4* rp = (const float4*)(src + row * D_DIM);
    float4 p0 = rp[lane * 2];
    float4 p1 = rp[lane * 2 + 1];

    float ss = p0.x*p0.x + p0.y*p0.y + p0.z*p0.z + p0.w*p0.w
             + p1.x*p1.x + p1.y*p1.y + p1.z*p1.z + p1.w*p1.w;
    #pragma unroll
    for (int m = 32; m >= 1; m >>= 1) ss += __shfl_xor(ss, m, 64);

    const float scale = 1.0f / fmaxf(sqrtf(ss), 1e-12f);

    bf16x8 v;
    v[0] = (__bf16)(p0.x * scale);
    v[1] = (__bf16)(p0.y * scale);
    v[2] = (__bf16)(p0.z * scale);
    v[3] = (__bf16)(p0.w * scale);
    v[4] = (__bf16)(p1.x * scale);
    v[5] = (__bf16)(p1.y * scale);
    v[6] = (__bf16)(p1.z * scale);
    v[7] = (__bf16)(p1.w * scale);
    *(bf16x8*)(drow + lane * 8) = v;
}

// ---------------------------------------------------------------------------
// bf16 MFMA GEMM (M=512, N=100096 padded, K=512) + fused ArcFace epilogue.
// 256x128 tile per block, 512 threads = 8 waves (4M x 2N), wave = 64x64 out.
//
// v3 (T4 counted-vmcnt): round-1 post-mortem showed __syncthreads() drains
// vmcnt(0), killing the prefetch (identical counters to round 0).  Fix:
//   * raw `s_barrier` via inline asm (no counter drain),
//   * counted `s_waitcnt vmcnt(4)` per K-step: retires exactly A(t),B(t),
//     leaves 4 loads (A(t+1)x2, B(t+1... t+2)) IN FLIGHT across barriers.
//   * A double-buffered (L3-hot, 1-iter cover), B TRIPLE-buffered (the
//     102 MB HBM/L3 W stream, 2-iter cover).  LDS 57 KB -> still 2 blk/CU
//     (occupancy is VGPR-bound at 2 blocks already; no loss).
//   * s_setprio(1) around the MFMA cluster (T5; a phase-split now exists).
// Issue order per iter t: [A(t+1)a, A(t+1)b, B(t+2)] -> in-order vmcnt
// retire makes vmcnt(4) == "A(t),B(t) complete".  Tail: vmcnt(3), vmcnt(0).
// Race audit: stage writes hit slots last read in compute(t-1), and the
// issue sits after the trailing barrier of t-1.  Barriers are uniform.
//
// LDS XOR swizzle (slot kc holds gmem chunk kc^((row>>1)&3)): 0 conflicts
// (measured).  Grid swizzle: paired m-tiles (ids b, b+8) share the n-tile's
// W panel through the same XCD's L2.
//
// Epilogue: phi/sqrt chain only where label==cls (~0.33 lanes per block!)
// -> rare-path branch; common path = clamp * S + store.
// ---------------------------------------------------------------------------
#define BM 256
#define BN 128
#define BK 32
#define KSTEPS  (D_DIM / BK)   // 16
#define N_TILES 782            // C_PAD / BN
#define GRID_B  1568           // 16 * ceil(N_TILES*2 / 16)

#define WAITVM(N) asm volatile("s_waitcnt vmcnt(" #N ")" ::: "memory")
#define BARRIER() asm volatile("s_barrier" ::: "memory")

__device__ inline void async_load_16B(__bf16* lds, const __bf16* gmem)
{
    __builtin_amdgcn_global_load_lds(
        (const __attribute__((address_space(1))) void*)gmem,
        (__attribute__((address_space(3))) void*)lds,
        16, 0, 0);
}

__global__ __launch_bounds__(512, 4) void gemm_arcface(
    const __bf16* __restrict__ A,
    const __bf16* __restrict__ W,
    const int*    __restrict__ label,
    float*        __restrict__ out)
{
    // XCD-aware swizzle: groups of 16 consecutive ids cover 8 n-tiles x 2
    // m-tiles such that the m-pair ids differ by exactly 8 (same XCD).
    const int b  = blockIdx.x;
    const int nt = (b & 7) + 8 * (b >> 4);
    const int mt = (b >> 3) & 1;
    if (nt >= N_TILES) return;   // uniform tail guard (8 idle blocks)

    __shared__ __bf16 As[2][BM * BK];   // 2 x 16 KB
    __shared__ __bf16 Bs[3][BN * BK];   // 3 x  8 KB
    __shared__ int    sLab[BM];

    const int tid = threadIdx.x;
    const int m0  = mt * BM;
    const int n0  = nt * BN;

    if (tid < BM) sLab[tid] = label[m0 + tid];

    const int lane = tid & 63;
    const int wave = tid >> 6;
    const int wr   = wave >> 1;        // 0..3 (M direction, 64 rows each)
    const int wc   = wave & 1;         // 0..1 (N direction, 64 cols each)
    const int frow = lane & 15;        // row within 16x16 frag
    const int fch  = lane >> 4;        // k-chunk sub-index 0..3

    // ---- staging descriptors (16B chunks; row = i>>2, kc = i&3) ----
    // (tid+512) has the same kc and (row>>1)&3 pattern: it is row+128.
    const int srow = tid >> 2;
    const int skc  = (tid & 3) ^ ((tid >> 3) & 3);   // swizzled gmem chunk

    const __bf16* gA0 = A + (long long)(m0 + srow) * D_DIM + skc * 8;
    const __bf16* gA1 = gA0 + (long long)128 * D_DIM;
    const __bf16* gB0 = W + (long long)(n0 + srow) * D_DIM + skc * 8;

    // ---- ds_read offsets (element units; fixed across K-loop) ----
    int aoff[4], boff[4];
    #pragma unroll
    for (int i = 0; i < 4; i++) {
        const int ar = wr * 64 + i * 16 + frow;
        aoff[i] = ar * BK + ((fch ^ ((ar >> 1) & 3)) << 3);
        const int br = wc * 64 + i * 16 + frow;
        boff[i] = br * BK + ((fch ^ ((br >> 1) & 3)) << 3);
    }

    floatx4 acc[4][4];
    #pragma unroll
    for (int i = 0; i < 4; i++)
        #pragma unroll
        for (int j = 0; j < 4; j++)
            acc[i][j] = (floatx4)(0.0f);

    // ---- prologue: A(0) -> As[0], B(0) -> Bs[0], B(1) -> Bs[1] ----
    async_load_16B(&As[0][tid * 8],         gA0);
    async_load_16B(&As[0][(tid + 512) * 8], gA1);
    async_load_16B(&Bs[0][tid * 8],         gB0);
    async_load_16B(&Bs[1][tid * 8],         gB0 + BK);

    // ---- K-loop: counted-vmcnt pipeline, fully unrolled (constexpr idx) --
    #pragma unroll
    for (int t = 0; t < KSTEPS; ++t) {
        if (t + 1 < KSTEPS) {          // stage A(t+1) -> As[(t+1)&1]
            const int u = t + 1;
            async_load_16B(&As[u & 1][tid * 8],         gA0 + u * BK);
            async_load_16B(&As[u & 1][(tid + 512) * 8], gA1 + u * BK);
        }
        if (t + 2 < KSTEPS) {          // stage B(t+2) -> Bs[(t+2)%3]
            const int u = t + 2;
            async_load_16B(&Bs[u % 3][tid * 8],         gB0 + u * BK);
        }

        // retire exactly through {B(t), A(t)}; keep the rest in flight
        if (t <= KSTEPS - 3)      WAITVM(4);
        else if (t == KSTEPS - 2) WAITVM(3);
        else                      WAITVM(0);
        BARRIER();                     // raw: does NOT drain vmcnt

        const __bf16* as = &As[t & 1][0];
        const __bf16* bs = &Bs[t % 3][0];
        bf16x8 a[4], bb[4];
        #pragma unroll
        for (int i = 0; i < 4; i++) a[i]  = *(const bf16x8*)(as + aoff[i]);
        #pragma unroll
        for (int j = 0; j < 4; j++) bb[j] = *(const bf16x8*)(bs + boff[j]);

        __builtin_amdgcn_s_setprio(1);
        #pragma unroll
        for (int i = 0; i < 4; i++)
            #pragma unroll
            for (int j = 0; j < 4; j++)
                acc[i][j] = __builtin_amdgcn_mfma_f32_16x16x32_bf16(
                    a[i], bb[j], acc[i][j], 0, 0, 0);
        __builtin_amdgcn_s_setprio(0);

        if (t + 1 < KSTEPS) BARRIER(); // readers done before next stage write
    }

    // ---- fused ArcFace epilogue ----
    // D layout: row (M) = (lane>>4)*4 + reg, col (N) = lane&15.
    // phi path is only needed where label==cls (~0.33 lanes/block) ->
    // rare-path branch; common path = clamp * S + store.
    const int mrow = (lane >> 4) * 4;
    const int ncol = lane & 15;

    #pragma unroll
    for (int i = 0; i < 4; i++) {
        #pragma unroll
        for (int r = 0; r < 4; r++) {
            const int ml  = wr * 64 + i * 16 + mrow + r;
            const int m   = m0 + ml;
            const int lab = sLab[ml];
            float* orow = out + (long long)m * C_CLS;
            #pragma unroll
            for (int j = 0; j < 4; j++) {
                const int cls = n0 + wc * 64 + j * 16 + ncol;
                if (cls < C_CLS) {
                    float c = fminf(fmaxf(acc[i][j][r], -1.0f), 1.0f);
                    float o = c * ARC_S;
                    if (lab == cls) {          // rare (easy-margin=False phi)
                        float tt  = fminf(fmaxf(1.0f - c * c, 1e-9f), 1.0f);
                        float s   = sqrtf(tt);
                        float phi = c * ARC_COSM - s * ARC_SINM;
                        phi = (c > ARC_TH) ? phi : (c - ARC_MM);
                        o = phi * ARC_S;
                    }
                    orow[cls] = o;
                }
            }
        }
    }
}

// ---------------------------------------------------------------------------
extern "C" void kernel_launch(void* const* d_in, const int* in_sizes, int n_in,
                              void* d_out, int out_size, void* d_ws, size_t ws_size,
                              hipStream_t stream)
{
    const float* inp    = (const float*)d_in[0];
    const int*   label  = (const int*)d_in[1];
    const float* weight = (const float*)d_in[2];
    float*       out    = (float*)d_out;

    // workspace layout: A_bf16 [512*512], W_bf16 [C_PAD*512]
    __bf16* A = (__bf16*)d_ws;
    __bf16* W = A + (size_t)B_ROWS * D_DIM;

    // K1: normalize input rows (512 rows, 4 rows/block)
    normalize_rows_512<<<B_ROWS / 4, 256, 0, stream>>>(inp, A, B_ROWS);
    // K2: normalize weight rows (+ zero-fill padding to C_PAD)
    normalize_rows_512<<<C_PAD / 4, 256, 0, stream>>>(weight, W, C_CLS);
    // K3: GEMM + ArcFace epilogue (counted-vmcnt pipeline, 256x128 tiles)
    gemm_arcface<<<GRID_B, 512, 0, stream>>>(A, W, label, out);
}